// Round 3
// baseline (1016.507 us; speedup 1.0000x reference)
//
#include <hip/hip_runtime.h>
#include <stdint.h>
#include <math.h>

// ---------------- constants ----------------
#define B_    4
#define L_    1024
#define H_    1024
#define NH_   16
#define M_    64
#define E_    24
#define R_    512
#define EMB_  768
#define BLK_  64
#define NCLS_ 97
#define NR_   2048        // B*R
#define KBIG_ 49152       // EMB*BLK  (bilinear GEMM K)

typedef unsigned short ushort_t;
typedef unsigned int uint_t;
typedef short bf16x8 __attribute__((ext_vector_type(8)));
typedef float f32x4  __attribute__((ext_vector_type(4)));

__device__ __forceinline__ float bf2f(ushort_t u) {
    return __uint_as_float(((unsigned)u) << 16);
}
__device__ __forceinline__ ushort_t f2bf_rne(float f) {
    unsigned u = __float_as_uint(f);
    return (ushort_t)((u + 0x7fffu + ((u >> 16) & 1u)) >> 16);
}
// scale a packed pair of bf16 (one dword) by h, repack (truncating) via v_perm
__device__ __forceinline__ uint_t pack2_scale(uint_t tw, float h) {
    float lo = __uint_as_float(tw << 16) * h;
    float hi = __uint_as_float(tw & 0xffff0000u) * h;
    return __builtin_amdgcn_perm(__float_as_uint(hi), __float_as_uint(lo), 0x07060302u);
}

// ---------------- transpose + f32->bf16 convert ----------------
// in: f32 [batch][rows][cols] ; out: bf16 [batch][cols][rows]
__global__ __launch_bounds__(256) void k_transpose_cvt(
    const float* __restrict__ in, ushort_t* __restrict__ out, int rows, int cols)
{
    __shared__ float t[64][65];
    int batch = blockIdx.z;
    in  += (size_t)batch * rows * cols;
    out += (size_t)batch * rows * cols;
    int c0 = blockIdx.x * 64, r0 = blockIdx.y * 64;
    int tx = threadIdx.x & 63, ty = threadIdx.x >> 6;   // 64 x 4
#pragma unroll
    for (int dr = 0; dr < 64; dr += 4)
        t[dr + ty][tx] = in[(size_t)(r0 + dr + ty) * cols + (c0 + tx)];
    __syncthreads();
    int c = threadIdx.x >> 2;            // 64 output rows (cols of in)
    int rk = (threadIdx.x & 3) * 16;     // 16 consecutive r per thread
    ushort_t us[16];
#pragma unroll
    for (int q = 0; q < 16; q++) us[q] = f2bf_rne(t[rk + q][c]);
    ushort_t* op = &out[(size_t)(c0 + c) * rows + r0 + rk];
    *reinterpret_cast<int4*>(op)     = *reinterpret_cast<const int4*>(&us[0]);
    *reinterpret_cast<int4*>(op + 8) = *reinterpret_cast<const int4*>(&us[8]);
}

// ---------------- entity embedding: logsumexp over mentions ----------------
__global__ __launch_bounds__(256) void k_ent_emb(
    const float* __restrict__ ent_lhs, const int* __restrict__ labels,
    float* __restrict__ ent_emb)
{
    int b = blockIdx.x / E_, e = blockIdx.x % E_;
    __shared__ int list[M_];
    __shared__ int cnt;
    if (threadIdx.x == 0) cnt = 0;
    __syncthreads();
    if (threadIdx.x < M_ && labels[b * M_ + threadIdx.x] == e) {
        int p = atomicAdd(&cnt, 1);
        list[p] = threadIdx.x;
    }
    __syncthreads();
    int n = cnt;
    const float* base = ent_lhs + (size_t)b * M_ * H_;
    float* outp = ent_emb + ((size_t)b * E_ + e) * H_;
    for (int h = threadIdx.x; h < H_; h += blockDim.x) {
        if (n == 0) { outp[h] = 0.f; continue; }
        float mx = -1e30f;
        for (int i = 0; i < n; i++) mx = fmaxf(mx, base[(size_t)list[i] * H_ + h]);
        float s = 0.f;
        for (int i = 0; i < n; i++) s += __expf(base[(size_t)list[i] * H_ + h] - mx);
        outp[h] = mx + __logf(s);
    }
}

// ---------------- entity attention: mean over mentions ----------------
__global__ __launch_bounds__(256) void k_ent_attn(
    const float* __restrict__ attn, const int* __restrict__ labels,
    float* __restrict__ ent_attn)
{
    int idx = blockIdx.x;                 // b*E*NH + e*NH + nh
    int nh = idx % NH_;
    int be = idx / NH_;
    int e = be % E_, b = be / E_;
    __shared__ int list[M_];
    __shared__ int cnt;
    if (threadIdx.x == 0) cnt = 0;
    __syncthreads();
    if (threadIdx.x < M_ && labels[b * M_ + threadIdx.x] == e) {
        int p = atomicAdd(&cnt, 1);
        list[p] = threadIdx.x;
    }
    __syncthreads();
    int n = cnt;
    float inv = 1.f / fmaxf((float)n, 1.f);
    const float* base = attn + ((size_t)b * NH_ + nh) * M_ * L_;
    float* outp = ent_attn + (((size_t)b * E_ + e) * NH_ + nh) * L_;
    for (int l = threadIdx.x; l < L_; l += blockDim.x) {
        float s = 0.f;
        for (int i = 0; i < n; i++) s += base[(size_t)list[i] * L_ + l];
        outp[l] = s * inv;
    }
}

// ---------------- per-pair ht: mean over heads of ha*ta, row-normalized ----------------
__global__ __launch_bounds__(256) void k_ht(
    const float* __restrict__ ent_attn, const int* __restrict__ hts,
    ushort_t* __restrict__ ht_bf)
{
    int b = blockIdx.x / R_, r = blockIdx.x % R_;
    int h = hts[((size_t)b * R_ + r) * 2 + 0];
    int t = hts[((size_t)b * R_ + r) * 2 + 1];
    const float* ha = ent_attn + ((size_t)b * E_ + h) * NH_ * L_;
    const float* ta = ent_attn + ((size_t)b * E_ + t) * NH_ * L_;
    float vals[4];
    float local = 0.f;
#pragma unroll
    for (int p = 0; p < 4; p++) {
        int l = threadIdx.x + p * 256;
        float s = 0.f;
#pragma unroll
        for (int nh = 0; nh < NH_; nh++) s += ha[nh * L_ + l] * ta[nh * L_ + l];
        s *= (1.f / NH_);
        vals[p] = s;
        local += s;
    }
    __shared__ float red[4];
    float s = local;
#pragma unroll
    for (int off = 32; off > 0; off >>= 1) s += __shfl_down(s, off, 64);
    if ((threadIdx.x & 63) == 0) red[threadIdx.x >> 6] = s;
    __syncthreads();
    float tot = red[0] + red[1] + red[2] + red[3];
    float inv = 1.f / (tot + 1e-5f);
    ushort_t* outp = ht_bf + ((size_t)b * R_ + r) * L_;
#pragma unroll
    for (int p = 0; p < 4; p++) {
        int l = threadIdx.x + p * 256;
        outp[l] = f2bf_rne(vals[p] * inv);
    }
}

// ---------------- gather hs/ts into concat buffers (cols 0..1023) ----------------
__global__ __launch_bounds__(256) void k_gather(
    const float* __restrict__ ent_emb, const int* __restrict__ hts,
    ushort_t* __restrict__ A1, ushort_t* __restrict__ A2)
{
    int n = blockIdx.x;
    int b = n / R_, r = n % R_;
    int h = hts[((size_t)b * R_ + r) * 2 + 0];
    int t = hts[((size_t)b * R_ + r) * 2 + 1];
    const float* eh = ent_emb + ((size_t)b * E_ + h) * H_;
    const float* et = ent_emb + ((size_t)b * E_ + t) * H_;
    for (int i = threadIdx.x; i < H_; i += 256) {
        A1[(size_t)n * 2048 + i] = f2bf_rne(eh[i]);
        A2[(size_t)n * 2048 + i] = f2bf_rne(et[i]);
    }
}

// ---------------- generic bf16 MFMA GEMM (A[M][K] rm  x  Bt[N][K] rm) ----------------
// tile 128x128, 4 waves (2x2 of 64x64), BK=64. Epilogue bounces through LDS for
// 16B vector bf16 stores (scalar 2B stores were 1/8-rate).
template <bool BIAS, bool TANH, bool DUAL>
__global__ __launch_bounds__(256) void k_gemm(
    const ushort_t* __restrict__ A, long sA, int lda,
    const ushort_t* __restrict__ Bt, long sB, int ldb,
    int K,
    const float* __restrict__ bias0, const float* __restrict__ bias1,
    ushort_t* __restrict__ C0, ushort_t* __restrict__ C1, long sC, int ldc)
{
    __shared__ ushort_t smem[2 * 128 * 72];   // As | Bs ; reused as 128x132 epilogue tile
    ushort_t* As = smem;
    ushort_t* Bs = smem + 128 * 72;
    const int tid = threadIdx.x;
    const int lane = tid & 63, wid = tid >> 6;
    const int wr = wid >> 1, wc = wid & 1;
    const int z = blockIdx.z;
    const int m0 = blockIdx.y * 128, n0 = blockIdx.x * 128;
    A  += (long)z * sA;
    Bt += (long)z * sB;

    const f32x4 zero = {0.f, 0.f, 0.f, 0.f};
    f32x4 acc[4][4];
#pragma unroll
    for (int i = 0; i < 4; i++)
#pragma unroll
        for (int j = 0; j < 4; j++) acc[i][j] = zero;

    const int mrow = wr * 64 + (lane & 15);
    const int nrow = wc * 64 + (lane & 15);
    const int koff = (lane >> 4) * 8;

    for (int k0 = 0; k0 < K; k0 += 64) {
        __syncthreads();
#pragma unroll
        for (int p = 0; p < 4; p++) {
            int idx = tid + p * 256;
            int row = idx >> 3, seg = idx & 7;
            *reinterpret_cast<int4*>(&As[row * 72 + seg * 8]) =
                *reinterpret_cast<const int4*>(&A[(long)(m0 + row) * lda + k0 + seg * 8]);
            *reinterpret_cast<int4*>(&Bs[row * 72 + seg * 8]) =
                *reinterpret_cast<const int4*>(&Bt[(long)(n0 + row) * ldb + k0 + seg * 8]);
        }
        __syncthreads();
#pragma unroll
        for (int ks = 0; ks < 2; ks++) {
            bf16x8 af[4], bfg[4];
#pragma unroll
            for (int mt = 0; mt < 4; mt++)
                af[mt] = *reinterpret_cast<const bf16x8*>(&As[(mrow + mt * 16) * 72 + ks * 32 + koff]);
#pragma unroll
            for (int nt = 0; nt < 4; nt++)
                bfg[nt] = *reinterpret_cast<const bf16x8*>(&Bs[(nrow + nt * 16) * 72 + ks * 32 + koff]);
#pragma unroll
            for (int mt = 0; mt < 4; mt++)
#pragma unroll
                for (int nt = 0; nt < 4; nt++)
                    acc[mt][nt] = __builtin_amdgcn_mfma_f32_16x16x32_bf16(
                        af[mt], bfg[nt], acc[mt][nt], 0, 0, 0);
        }
    }

    // epilogue: bias/tanh -> bf16 -> LDS (stride 132 kills quad bank conflicts) -> 16B stores
    const float* bias = BIAS ? (z ? bias1 : bias0) : nullptr;
    __syncthreads();
#pragma unroll
    for (int mt = 0; mt < 4; mt++) {
#pragma unroll
        for (int nt = 0; nt < 4; nt++) {
#pragma unroll
            for (int rg = 0; rg < 4; rg++) {
                int row = wr * 64 + mt * 16 + (lane >> 4) * 4 + rg;   // 0..127 local
                int col = wc * 64 + nt * 16 + (lane & 15);            // 0..127 local
                float v = acc[mt][nt][rg];
                if (BIAS) v += bias[n0 + col];
                if (TANH) {
                    float vc = fminf(fmaxf(v, -15.f), 15.f);
                    float ex = __expf(2.f * vc);
                    v = (ex - 1.f) / (ex + 1.f);
                }
                smem[row * 132 + col] = f2bf_rne(v);
            }
        }
    }
    __syncthreads();
    {
        int row = tid >> 1, half = tid & 1;
        const ushort_t* src = &smem[row * 132 + half * 64];
        ushort_t* dst0 = &C0[(long)z * sC + (long)(m0 + row) * ldc + n0 + half * 64];
#pragma unroll
        for (int q = 0; q < 8; q++)
            *reinterpret_cast<int4*>(dst0 + q * 8) = *reinterpret_cast<const int4*>(src + q * 8);
        if (DUAL) {
            ushort_t* dst1 = &C1[(long)z * sC + (long)(m0 + row) * ldc + n0 + half * 64];
#pragma unroll
            for (int q = 0; q < 8; q++)
                *reinterpret_cast<int4*>(dst1 + q * 8) = *reinterpret_cast<const int4*>(src + q * 8);
        }
    }
}

// ---------------- bilinear GEMM: embeds[z-slice] = (he (x) te blocks) @ Wb ----------------
// 1536 blocks = 96 spatial x 16 K-slices (48 chunks each) -> exactly 3 rounds at
// 2 blocks/CU (no fractional tail). z = ((bid&7)<<1)|((bid>>3)&1): each XCD owns a
// contiguous 9.4 MB Wbt window (L2 reuse). Waves: 4 x (32n x 128d) -> pack VALU per
// MFMA halves vs 64x64. B-frags software-pipelined (ping-pong b0/b1, prefetch i+1).
__global__ __launch_bounds__(256) void k_bilinear(
    const ushort_t* __restrict__ he, const ushort_t* __restrict__ te,
    const ushort_t* __restrict__ Wbt, float* __restrict__ embedsN, int slices)
{
    __shared__ ushort_t HEs[128 * 72];
    const int tid = threadIdx.x;
    const int lane = tid & 63;
    const int wr = tid >> 6;                       // wave = 32 rows x 128 cols
    const int bid = blockIdx.x;
    const int z = ((bid & 7) << 1) | ((bid >> 3) & 1);
    const int w = bid >> 4;
    const int d0 = (w % 6) * 128, n0 = (w / 6) * 128;
    const int c0 = z * 48, cend = c0 + 48;

    const f32x4 zero = {0.f, 0.f, 0.f, 0.f};
    f32x4 acc[2][8];
#pragma unroll
    for (int i = 0; i < 2; i++)
#pragma unroll
        for (int j = 0; j < 8; j++) acc[i][j] = zero;

    const int r15 = lane & 15;
    const int mrow = wr * 32 + r15;
    const int koff = (lane >> 4) * 8;

    int c = c0;
    while (c < cend) {
        const int kk = c >> 6;
        const int i0 = c & 63;
        const int i1 = min(64, i0 + (cend - c));

        // stage he[n0..n0+128][kk*64..+64] into LDS (row-major, stride 72)
        __syncthreads();
#pragma unroll
        for (int p = 0; p < 4; p++) {
            int idx = tid + p * 256;
            int row = idx >> 3, seg = idx & 7;
            *reinterpret_cast<int4*>(&HEs[row * 72 + seg * 8]) =
                *reinterpret_cast<const int4*>(&he[(long)(n0 + row) * EMB_ + kk * 64 + seg * 8]);
        }
        __syncthreads();

        // te fragments for this kk-group: straight from global into registers
        uint4 tef[2][2];
#pragma unroll
        for (int mt = 0; mt < 2; mt++)
#pragma unroll
            for (int ks = 0; ks < 2; ks++)
                tef[mt][ks] = *reinterpret_cast<const uint4*>(
                    &te[(long)(n0 + mrow + mt * 16) * EMB_ + kk * 64 + ks * 32 + koff]);

        int4 b0[8][2], b1[8][2];
        auto load_bfr = [&](int4 (&b)[8][2], int i) {
            const long kb = (long)(kk * 64 + i) * 64 + koff;
#pragma unroll
            for (int nt = 0; nt < 8; nt++) {
                const ushort_t* p = &Wbt[(long)(d0 + nt * 16 + r15) * KBIG_ + kb];
                b[nt][0] = *reinterpret_cast<const int4*>(p);
                b[nt][1] = *reinterpret_cast<const int4*>(p + 32);
            }
        };
        auto compute = [&](int4 (&b)[8][2], int i) {
#pragma unroll
            for (int mt = 0; mt < 2; mt++) {
                float h = bf2f(HEs[(mrow + mt * 16) * 72 + i]);
#pragma unroll
                for (int ks = 0; ks < 2; ks++) {
                    uint4 t = tef[mt][ks];
                    union { uint_t u[4]; bf16x8 v; } a;
                    a.u[0] = pack2_scale(t.x, h);
                    a.u[1] = pack2_scale(t.y, h);
                    a.u[2] = pack2_scale(t.z, h);
                    a.u[3] = pack2_scale(t.w, h);
#pragma unroll
                    for (int nt = 0; nt < 8; nt++)
                        acc[mt][nt] = __builtin_amdgcn_mfma_f32_16x16x32_bf16(
                            a.v, *reinterpret_cast<const bf16x8*>(&b[nt][ks]), acc[mt][nt], 0, 0, 0);
                }
            }
        };

        load_bfr(b0, i0);
        int i = i0;
        while (i + 2 <= i1) {                       // i-counts are multiples of 16
            load_bfr(b1, i + 1);
            compute(b0, i);
            load_bfr(b0, (i + 2 < i1) ? i + 2 : i + 1);
            compute(b1, i + 1);
            i += 2;
        }
        if (i < i1) compute(b0, i);
        c += (i1 - i0);
    }

    // epilogue: plain fp32 stores into slice (z*slices/16), atomic if slices<16
    const int sl = (z * slices) >> 4;
    float* outp = embedsN + (long)sl * NR_ * EMB_;
    const bool plain = (slices == 16);
#pragma unroll
    for (int mt = 0; mt < 2; mt++)
#pragma unroll
        for (int nt = 0; nt < 8; nt++)
#pragma unroll
            for (int rg = 0; rg < 4; rg++) {
                int n = n0 + wr * 32 + mt * 16 + (lane >> 4) * 4 + rg;
                int d = d0 + nt * 16 + r15;
                if (plain) outp[(long)n * EMB_ + d] = acc[mt][nt][rg];
                else       atomicAdd(&outp[(long)n * EMB_ + d], acc[mt][nt][rg]);
            }
}

// ---------------- final head: out = (sum_z embeds + bb) @ Wc + bc  (fp32) ----------------
__global__ __launch_bounds__(128) void k_final(
    const float* __restrict__ embedsN, int nz, const float* __restrict__ bb,
    const float* __restrict__ Wc, const float* __restrict__ bc,
    float* __restrict__ out)
{
    int n = blockIdx.x;
    __shared__ float row[EMB_];
    for (int i = threadIdx.x; i < EMB_; i += 128) {
        float s = bb[i];
        for (int zz = 0; zz < nz; zz++)
            s += embedsN[(size_t)zz * NR_ * EMB_ + (size_t)n * EMB_ + i];
        row[i] = s;
    }
    __syncthreads();
    int j = threadIdx.x;
    if (j < NCLS_) {
        float s = bc[j];
#pragma unroll 8
        for (int d = 0; d < EMB_; d++) s += row[d] * Wc[d * NCLS_ + j];
        out[(size_t)n * NCLS_ + j] = s;
    }
}

// ---------------- launcher ----------------
extern "C" void kernel_launch(void* const* d_in, const int* in_sizes, int n_in,
                              void* d_out, int out_size, void* d_ws, size_t ws_size,
                              hipStream_t stream)
{
    (void)in_sizes; (void)n_in; (void)out_size;
    const float* seq    = (const float*)d_in[0];
    const float* entl   = (const float*)d_in[1];
    const float* attn   = (const float*)d_in[2];
    const int*   labels = (const int*)d_in[3];
    const int*   hts    = (const int*)d_in[4];
    const float* Wh     = (const float*)d_in[5];
    const float* bh     = (const float*)d_in[6];
    const float* Wt     = (const float*)d_in[7];
    const float* bt     = (const float*)d_in[8];
    const float* Wb     = (const float*)d_in[9];
    const float* bb     = (const float*)d_in[10];
    const float* Wc     = (const float*)d_in[11];
    const float* bc     = (const float*)d_in[12];
    float* out = (float*)d_out;

    char* ws = (char*)d_ws;
    size_t off = 0;
    auto alloc = [&](size_t bytes) -> char* {
        char* p = ws + off;
        off += (bytes + 255) & ~(size_t)255;
        return p;
    };
    float*    ent_emb  = (float*)alloc((size_t)B_ * E_ * H_ * 4);
    float*    ent_attn = (float*)alloc((size_t)B_ * E_ * NH_ * L_ * 4);
    ushort_t* ht_bf    = (ushort_t*)alloc((size_t)B_ * R_ * L_ * 2);
    ushort_t* seq_t    = (ushort_t*)alloc((size_t)B_ * H_ * L_ * 2);
    ushort_t* A1       = (ushort_t*)alloc((size_t)NR_ * 2048 * 2);   // [hs | rel]
    ushort_t* A2       = (ushort_t*)alloc((size_t)NR_ * 2048 * 2);   // [ts | rel] (adjacent)
    ushort_t* Whb      = (ushort_t*)alloc((size_t)EMB_ * 2048 * 2);  // Wh^T bf16
    ushort_t* Wtb      = (ushort_t*)alloc((size_t)EMB_ * 2048 * 2);  // adjacent to Whb
    ushort_t* he_bf    = (ushort_t*)alloc((size_t)NR_ * EMB_ * 2);
    ushort_t* te_bf    = (ushort_t*)alloc((size_t)NR_ * EMB_ * 2);   // adjacent to he_bf
    ushort_t* Wbt      = (ushort_t*)alloc((size_t)EMB_ * KBIG_ * 2); // Wb^T bf16 [768][49152]

    const size_t slice_b = (size_t)NR_ * EMB_ * 4;
    int slices = (ws_size >= off + 16 * slice_b) ? 16
               : (ws_size >= off + 8 * slice_b)  ? 8 : 1;
    float* embedsN = (float*)alloc((size_t)slices * slice_b);

    // 1) transposed bf16 copies of weights / seq
    k_transpose_cvt<<<dim3(H_ / 64, L_ / 64, B_), 256, 0, stream>>>(seq, seq_t, L_, H_);
    k_transpose_cvt<<<dim3(EMB_ / 64, 2048 / 64, 1), 256, 0, stream>>>(Wh, Whb, 2048, EMB_);
    k_transpose_cvt<<<dim3(EMB_ / 64, 2048 / 64, 1), 256, 0, stream>>>(Wt, Wtb, 2048, EMB_);
    k_transpose_cvt<<<dim3(EMB_ / 64, KBIG_ / 64, 1), 256, 0, stream>>>(Wb, Wbt, KBIG_, EMB_);

    // 2) entity aggregation
    k_ent_emb<<<B_ * E_, 256, 0, stream>>>(entl, labels, ent_emb);
    k_ent_attn<<<B_ * E_ * NH_, 256, 0, stream>>>(attn, labels, ent_attn);

    // 3) pair attention rows + gathers
    k_ht<<<NR_, 256, 0, stream>>>(ent_attn, hts, ht_bf);
    k_gather<<<NR_, 256, 0, stream>>>(ent_emb, hts, A1, A2);

    // 4) rel = ht @ seq  (batched over B), written bf16 into cols 1024.. of A1 and A2
    k_gemm<false, false, true><<<dim3(H_ / 128, R_ / 128, B_), 256, 0, stream>>>(
        ht_bf, (long)R_ * L_, L_,
        seq_t, (long)H_ * L_, L_,
        L_, nullptr, nullptr,
        A1 + 1024, A2 + 1024, (long)R_ * 2048, 2048);

    // 5) he = tanh(A1 @ Wh + bh), te = tanh(A2 @ Wt + bt)   (z selects the pair)
    k_gemm<true, true, false><<<dim3(EMB_ / 128, NR_ / 128, 2), 256, 0, stream>>>(
        A1, (long)NR_ * 2048, 2048,
        Whb, (long)EMB_ * 2048, 2048,
        2048, bh, bt,
        he_bf, nullptr, (long)NR_ * EMB_, EMB_);

    // 6) embeds = bl @ Wb  (A generated on the fly; 16 K-slices, XCD-mapped, pipelined)
    if (slices < 16)
        (void)hipMemsetAsync(embedsN, 0, (size_t)slices * slice_b, stream);
    k_bilinear<<<1536, 256, 0, stream>>>(he_bf, te_bf, Wbt, embedsN, slices);

    // 7) out = (sum_z embeds + bb) @ Wc + bc   (fp32)
    k_final<<<NR_, 128, 0, stream>>>(embedsN, slices, bb, Wc, bc, out);
}

// Round 4
// 736.735 us; speedup vs baseline: 1.3797x; 1.3797x over previous
//
#include <hip/hip_runtime.h>
#include <stdint.h>
#include <math.h>

// ---------------- constants ----------------
#define B_    4
#define L_    1024
#define H_    1024
#define NH_   16
#define M_    64
#define E_    24
#define R_    512
#define EMB_  768
#define BLK_  64
#define NCLS_ 97
#define NR_   2048        // B*R
#define KBIG_ 49152       // EMB*BLK  (bilinear GEMM K)

typedef unsigned short ushort_t;
typedef unsigned int uint_t;
typedef short bf16x8 __attribute__((ext_vector_type(8)));
typedef float f32x4  __attribute__((ext_vector_type(4)));
typedef __bf16 bf16v2 __attribute__((ext_vector_type(2)));

__device__ __forceinline__ float bf2f(ushort_t u) {
    return __uint_as_float(((unsigned)u) << 16);
}
__device__ __forceinline__ ushort_t f2bf_rne(float f) {
    unsigned u = __float_as_uint(f);
    return (ushort_t)((u + 0x7fffu + ((u >> 16) & 1u)) >> 16);
}

// ---------------- transpose + f32->bf16 convert ----------------
// in: f32 [batch][rows][cols] ; out: bf16 [batch][cols][rows]
__global__ __launch_bounds__(256) void k_transpose_cvt(
    const float* __restrict__ in, ushort_t* __restrict__ out, int rows, int cols)
{
    __shared__ float t[64][65];
    int batch = blockIdx.z;
    in  += (size_t)batch * rows * cols;
    out += (size_t)batch * rows * cols;
    int c0 = blockIdx.x * 64, r0 = blockIdx.y * 64;
    int tx = threadIdx.x & 63, ty = threadIdx.x >> 6;   // 64 x 4
#pragma unroll
    for (int dr = 0; dr < 64; dr += 4)
        t[dr + ty][tx] = in[(size_t)(r0 + dr + ty) * cols + (c0 + tx)];
    __syncthreads();
    int c = threadIdx.x >> 2;            // 64 output rows (cols of in)
    int rk = (threadIdx.x & 3) * 16;     // 16 consecutive r per thread
    ushort_t us[16];
#pragma unroll
    for (int q = 0; q < 16; q++) us[q] = f2bf_rne(t[rk + q][c]);
    ushort_t* op = &out[(size_t)(c0 + c) * rows + r0 + rk];
    *reinterpret_cast<int4*>(op)     = *reinterpret_cast<const int4*>(&us[0]);
    *reinterpret_cast<int4*>(op + 8) = *reinterpret_cast<const int4*>(&us[8]);
}

// ---------------- entity embedding: logsumexp over mentions ----------------
__global__ __launch_bounds__(256) void k_ent_emb(
    const float* __restrict__ ent_lhs, const int* __restrict__ labels,
    float* __restrict__ ent_emb)
{
    int b = blockIdx.x / E_, e = blockIdx.x % E_;
    __shared__ int list[M_];
    __shared__ int cnt;
    if (threadIdx.x == 0) cnt = 0;
    __syncthreads();
    if (threadIdx.x < M_ && labels[b * M_ + threadIdx.x] == e) {
        int p = atomicAdd(&cnt, 1);
        list[p] = threadIdx.x;
    }
    __syncthreads();
    int n = cnt;
    const float* base = ent_lhs + (size_t)b * M_ * H_;
    float* outp = ent_emb + ((size_t)b * E_ + e) * H_;
    for (int h = threadIdx.x; h < H_; h += blockDim.x) {
        if (n == 0) { outp[h] = 0.f; continue; }
        float mx = -1e30f;
        for (int i = 0; i < n; i++) mx = fmaxf(mx, base[(size_t)list[i] * H_ + h]);
        float s = 0.f;
        for (int i = 0; i < n; i++) s += __expf(base[(size_t)list[i] * H_ + h] - mx);
        outp[h] = mx + __logf(s);
    }
}

// ---------------- entity attention: mean over mentions ----------------
__global__ __launch_bounds__(256) void k_ent_attn(
    const float* __restrict__ attn, const int* __restrict__ labels,
    float* __restrict__ ent_attn)
{
    int idx = blockIdx.x;                 // b*E*NH + e*NH + nh
    int nh = idx % NH_;
    int be = idx / NH_;
    int e = be % E_, b = be / E_;
    __shared__ int list[M_];
    __shared__ int cnt;
    if (threadIdx.x == 0) cnt = 0;
    __syncthreads();
    if (threadIdx.x < M_ && labels[b * M_ + threadIdx.x] == e) {
        int p = atomicAdd(&cnt, 1);
        list[p] = threadIdx.x;
    }
    __syncthreads();
    int n = cnt;
    float inv = 1.f / fmaxf((float)n, 1.f);
    const float* base = attn + ((size_t)b * NH_ + nh) * M_ * L_;
    float* outp = ent_attn + (((size_t)b * E_ + e) * NH_ + nh) * L_;
    for (int l = threadIdx.x; l < L_; l += blockDim.x) {
        float s = 0.f;
        for (int i = 0; i < n; i++) s += base[(size_t)list[i] * L_ + l];
        outp[l] = s * inv;
    }
}

// ---------------- per-pair ht: mean over heads of ha*ta, row-normalized ----------------
__global__ __launch_bounds__(256) void k_ht(
    const float* __restrict__ ent_attn, const int* __restrict__ hts,
    ushort_t* __restrict__ ht_bf)
{
    int b = blockIdx.x / R_, r = blockIdx.x % R_;
    int h = hts[((size_t)b * R_ + r) * 2 + 0];
    int t = hts[((size_t)b * R_ + r) * 2 + 1];
    const float* ha = ent_attn + ((size_t)b * E_ + h) * NH_ * L_;
    const float* ta = ent_attn + ((size_t)b * E_ + t) * NH_ * L_;
    float vals[4];
    float local = 0.f;
#pragma unroll
    for (int p = 0; p < 4; p++) {
        int l = threadIdx.x + p * 256;
        float s = 0.f;
#pragma unroll
        for (int nh = 0; nh < NH_; nh++) s += ha[nh * L_ + l] * ta[nh * L_ + l];
        s *= (1.f / NH_);
        vals[p] = s;
        local += s;
    }
    __shared__ float red[4];
    float s = local;
#pragma unroll
    for (int off = 32; off > 0; off >>= 1) s += __shfl_down(s, off, 64);
    if ((threadIdx.x & 63) == 0) red[threadIdx.x >> 6] = s;
    __syncthreads();
    float tot = red[0] + red[1] + red[2] + red[3];
    float inv = 1.f / (tot + 1e-5f);
    ushort_t* outp = ht_bf + ((size_t)b * R_ + r) * L_;
#pragma unroll
    for (int p = 0; p < 4; p++) {
        int l = threadIdx.x + p * 256;
        outp[l] = f2bf_rne(vals[p] * inv);
    }
}

// ---------------- gather hs/ts into concat buffers (cols 0..1023) ----------------
__global__ __launch_bounds__(256) void k_gather(
    const float* __restrict__ ent_emb, const int* __restrict__ hts,
    ushort_t* __restrict__ A1, ushort_t* __restrict__ A2)
{
    int n = blockIdx.x;
    int b = n / R_, r = n % R_;
    int h = hts[((size_t)b * R_ + r) * 2 + 0];
    int t = hts[((size_t)b * R_ + r) * 2 + 1];
    const float* eh = ent_emb + ((size_t)b * E_ + h) * H_;
    const float* et = ent_emb + ((size_t)b * E_ + t) * H_;
    for (int i = threadIdx.x; i < H_; i += 256) {
        A1[(size_t)n * 2048 + i] = f2bf_rne(eh[i]);
        A2[(size_t)n * 2048 + i] = f2bf_rne(et[i]);
    }
}

// ---------------- generic bf16 MFMA GEMM (A[M][K] rm  x  Bt[N][K] rm) ----------------
// tile 128x128, 4 waves (2x2 of 64x64), BK=64. Epilogue bounces through LDS for
// 16B vector bf16 stores.
template <bool BIAS, bool TANH, bool DUAL>
__global__ __launch_bounds__(256) void k_gemm(
    const ushort_t* __restrict__ A, long sA, int lda,
    const ushort_t* __restrict__ Bt, long sB, int ldb,
    int K,
    const float* __restrict__ bias0, const float* __restrict__ bias1,
    ushort_t* __restrict__ C0, ushort_t* __restrict__ C1, long sC, int ldc)
{
    __shared__ ushort_t smem[2 * 128 * 72];   // As | Bs ; reused as 128x132 epilogue tile
    ushort_t* As = smem;
    ushort_t* Bs = smem + 128 * 72;
    const int tid = threadIdx.x;
    const int lane = tid & 63, wid = tid >> 6;
    const int wr = wid >> 1, wc = wid & 1;
    const int z = blockIdx.z;
    const int m0 = blockIdx.y * 128, n0 = blockIdx.x * 128;
    A  += (long)z * sA;
    Bt += (long)z * sB;

    const f32x4 zero = {0.f, 0.f, 0.f, 0.f};
    f32x4 acc[4][4];
#pragma unroll
    for (int i = 0; i < 4; i++)
#pragma unroll
        for (int j = 0; j < 4; j++) acc[i][j] = zero;

    const int mrow = wr * 64 + (lane & 15);
    const int nrow = wc * 64 + (lane & 15);
    const int koff = (lane >> 4) * 8;

    for (int k0 = 0; k0 < K; k0 += 64) {
        __syncthreads();
#pragma unroll
        for (int p = 0; p < 4; p++) {
            int idx = tid + p * 256;
            int row = idx >> 3, seg = idx & 7;
            *reinterpret_cast<int4*>(&As[row * 72 + seg * 8]) =
                *reinterpret_cast<const int4*>(&A[(long)(m0 + row) * lda + k0 + seg * 8]);
            *reinterpret_cast<int4*>(&Bs[row * 72 + seg * 8]) =
                *reinterpret_cast<const int4*>(&Bt[(long)(n0 + row) * ldb + k0 + seg * 8]);
        }
        __syncthreads();
#pragma unroll
        for (int ks = 0; ks < 2; ks++) {
            bf16x8 af[4], bfg[4];
#pragma unroll
            for (int mt = 0; mt < 4; mt++)
                af[mt] = *reinterpret_cast<const bf16x8*>(&As[(mrow + mt * 16) * 72 + ks * 32 + koff]);
#pragma unroll
            for (int nt = 0; nt < 4; nt++)
                bfg[nt] = *reinterpret_cast<const bf16x8*>(&Bs[(nrow + nt * 16) * 72 + ks * 32 + koff]);
#pragma unroll
            for (int mt = 0; mt < 4; mt++)
#pragma unroll
                for (int nt = 0; nt < 4; nt++)
                    acc[mt][nt] = __builtin_amdgcn_mfma_f32_16x16x32_bf16(
                        af[mt], bfg[nt], acc[mt][nt], 0, 0, 0);
        }
    }

    // epilogue: bias/tanh -> bf16 -> LDS (stride 132) -> 16B stores
    const float* bias = BIAS ? (z ? bias1 : bias0) : nullptr;
    __syncthreads();
#pragma unroll
    for (int mt = 0; mt < 4; mt++) {
#pragma unroll
        for (int nt = 0; nt < 4; nt++) {
#pragma unroll
            for (int rg = 0; rg < 4; rg++) {
                int row = wr * 64 + mt * 16 + (lane >> 4) * 4 + rg;   // 0..127 local
                int col = wc * 64 + nt * 16 + (lane & 15);            // 0..127 local
                float v = acc[mt][nt][rg];
                if (BIAS) v += bias[n0 + col];
                if (TANH) {
                    float vc = fminf(fmaxf(v, -15.f), 15.f);
                    float ex = __expf(2.f * vc);
                    v = (ex - 1.f) / (ex + 1.f);
                }
                smem[row * 132 + col] = f2bf_rne(v);
            }
        }
    }
    __syncthreads();
    {
        int row = tid >> 1, half = tid & 1;
        const ushort_t* src = &smem[row * 132 + half * 64];
        ushort_t* dst0 = &C0[(long)z * sC + (long)(m0 + row) * ldc + n0 + half * 64];
#pragma unroll
        for (int q = 0; q < 8; q++)
            *reinterpret_cast<int4*>(dst0 + q * 8) = *reinterpret_cast<const int4*>(src + q * 8);
        if (DUAL) {
            ushort_t* dst1 = &C1[(long)z * sC + (long)(m0 + row) * ldc + n0 + half * 64];
#pragma unroll
            for (int q = 0; q < 8; q++)
                *reinterpret_cast<int4*>(dst1 + q * 8) = *reinterpret_cast<const int4*>(src + q * 8);
        }
    }
}

// ---------------- bilinear GEMM: embeds[z] = (he (x) te blocks) @ Wb (K-slice z) ----------
// ROUND-2 STRUCTURE (proven: FETCH ~= compulsory): 768 blocks, z = bid&7 -> one
// 9.4 MB Wbt window per XCD, 96 co-resident blocks in lockstep. 4 waves as 2x2
// of 64x64 (B-frag reused by mt=4 MFMAs). NEW: ping-pong prefetch of B-frags
// (i+1 in flight during compute(i)) + v_pk_mul_bf16 A-scaling (1 inst/dword).
__global__ __launch_bounds__(256) void k_bilinear(
    const ushort_t* __restrict__ he, const ushort_t* __restrict__ te,
    const ushort_t* __restrict__ Wbt, float* __restrict__ embedsN, int slices)
{
    __shared__ ushort_t HEs[128 * 72];
    const int tid = threadIdx.x;
    const int lane = tid & 63, wid = tid >> 6;
    const int wr = wid >> 1, wc = wid & 1;
    const int bid = blockIdx.x;
    const int z = bid & 7;            // K-slice == XCD (round-robin dispatch heuristic)
    const int w = bid >> 3;
    const int d0 = (w % 6) * 128, n0 = (w / 6) * 128;
    const int c0 = z * 96, cend = c0 + 96;

    const f32x4 zero = {0.f, 0.f, 0.f, 0.f};
    f32x4 acc[4][4];
#pragma unroll
    for (int i = 0; i < 4; i++)
#pragma unroll
        for (int j = 0; j < 4; j++) acc[i][j] = zero;

    const int r15 = lane & 15;
    const int mrow = wr * 64 + r15;        // wave's n-row id (m = lane&15 of A-frag)
    const int koff = (lane >> 4) * 8;

    // per-wave Wbt row base pointers (d-columns of this wave)
    const ushort_t* wbp[4];
#pragma unroll
    for (int nt = 0; nt < 4; nt++)
        wbp[nt] = Wbt + (long)(d0 + wc * 64 + nt * 16 + r15) * KBIG_ + koff;

    int c = c0;
    while (c < cend) {
        const int kk = c >> 6;
        const int i0 = c & 63;
        const int i1 = min(64, i0 + (cend - c));

        // stage he[n0..n0+128][kk*64..+64] into LDS (row-major, stride 72)
        __syncthreads();
#pragma unroll
        for (int p = 0; p < 4; p++) {
            int idx = tid + p * 256;
            int row = idx >> 3, seg = idx & 7;
            *reinterpret_cast<int4*>(&HEs[row * 72 + seg * 8]) =
                *reinterpret_cast<const int4*>(&he[(long)(n0 + row) * EMB_ + kk * 64 + seg * 8]);
        }
        __syncthreads();

        // te fragments for this kk-group: global -> registers (reused over all i)
        uint4 tef[4][2];
#pragma unroll
        for (int mt = 0; mt < 4; mt++)
#pragma unroll
            for (int ks = 0; ks < 2; ks++)
                tef[mt][ks] = *reinterpret_cast<const uint4*>(
                    &te[(long)(n0 + mrow + mt * 16) * EMB_ + kk * 64 + ks * 32 + koff]);

        int4 b0[4][2], b1[4][2];
        auto load_b = [&](int4 (&b)[4][2], int i) {
            const long kb = (long)(kk * 64 + i) * 64;
#pragma unroll
            for (int nt = 0; nt < 4; nt++) {
                const ushort_t* p = wbp[nt] + kb;
                b[nt][0] = *reinterpret_cast<const int4*>(p);
                b[nt][1] = *reinterpret_cast<const int4*>(p + 32);
            }
        };
        auto compute = [&](int4 (&b)[4][2], int i) {
#pragma unroll
            for (int mt = 0; mt < 4; mt++) {
                union { ushort_t s[2]; bf16v2 v; } hu;
                ushort_t hbits = HEs[(mrow + mt * 16) * 72 + i];
                hu.s[0] = hbits; hu.s[1] = hbits;
                const bf16v2 hh = hu.v;
#pragma unroll
                for (int ks = 0; ks < 2; ks++) {
                    union U { uint4 q; bf16v2 p[4]; bf16x8 v; };
                    U t, a;
                    t.q = tef[mt][ks];
#pragma unroll
                    for (int qq = 0; qq < 4; qq++) a.p[qq] = t.p[qq] * hh;  // v_pk_mul_bf16
#pragma unroll
                    for (int nt = 0; nt < 4; nt++)
                        acc[mt][nt] = __builtin_amdgcn_mfma_f32_16x16x32_bf16(
                            a.v, *reinterpret_cast<const bf16x8*>(&b[nt][ks]), acc[mt][nt], 0, 0, 0);
                }
            }
        };

        // software pipeline: B-frags for i+1 in flight while computing i
        load_b(b0, i0);
        int i = i0;
        for (; i + 2 <= i1; i += 2) {
            load_b(b1, i + 1);
            compute(b0, i);
            if (i + 2 < i1) load_b(b0, i + 2);
            compute(b1, i + 1);
        }
        if (i < i1) compute(b0, i);     // (i1-i0 is even here; kept for safety)
        c += (i1 - i0);
    }

    // epilogue: plain fp32 stores into slice z (slices==8), else atomic into slice 0
    float* outp = embedsN + (slices == 8 ? (long)z * NR_ * EMB_ : 0l);
    const bool plain = (slices == 8);
#pragma unroll
    for (int mt = 0; mt < 4; mt++)
#pragma unroll
        for (int nt = 0; nt < 4; nt++)
#pragma unroll
            for (int rg = 0; rg < 4; rg++) {
                int n = n0 + wr * 64 + mt * 16 + (lane >> 4) * 4 + rg;
                int d = d0 + wc * 64 + nt * 16 + r15;
                if (plain) outp[(long)n * EMB_ + d] = acc[mt][nt][rg];
                else       atomicAdd(&outp[(long)n * EMB_ + d], acc[mt][nt][rg]);
            }
}

// ---------------- final head: out = (sum_z embeds + bb) @ Wc + bc  (fp32) ----------------
__global__ __launch_bounds__(128) void k_final(
    const float* __restrict__ embedsN, int nz, const float* __restrict__ bb,
    const float* __restrict__ Wc, const float* __restrict__ bc,
    float* __restrict__ out)
{
    int n = blockIdx.x;
    __shared__ float row[EMB_];
    for (int i = threadIdx.x; i < EMB_; i += 128) {
        float s = bb[i];
        for (int zz = 0; zz < nz; zz++)
            s += embedsN[(size_t)zz * NR_ * EMB_ + (size_t)n * EMB_ + i];
        row[i] = s;
    }
    __syncthreads();
    int j = threadIdx.x;
    if (j < NCLS_) {
        float s = bc[j];
#pragma unroll 8
        for (int d = 0; d < EMB_; d++) s += row[d] * Wc[d * NCLS_ + j];
        out[(size_t)n * NCLS_ + j] = s;
    }
}

// ---------------- launcher ----------------
extern "C" void kernel_launch(void* const* d_in, const int* in_sizes, int n_in,
                              void* d_out, int out_size, void* d_ws, size_t ws_size,
                              hipStream_t stream)
{
    (void)in_sizes; (void)n_in; (void)out_size;
    const float* seq    = (const float*)d_in[0];
    const float* entl   = (const float*)d_in[1];
    const float* attn   = (const float*)d_in[2];
    const int*   labels = (const int*)d_in[3];
    const int*   hts    = (const int*)d_in[4];
    const float* Wh     = (const float*)d_in[5];
    const float* bh     = (const float*)d_in[6];
    const float* Wt     = (const float*)d_in[7];
    const float* bt     = (const float*)d_in[8];
    const float* Wb     = (const float*)d_in[9];
    const float* bb     = (const float*)d_in[10];
    const float* Wc     = (const float*)d_in[11];
    const float* bc     = (const float*)d_in[12];
    float* out = (float*)d_out;

    char* ws = (char*)d_ws;
    size_t off = 0;
    auto alloc = [&](size_t bytes) -> char* {
        char* p = ws + off;
        off += (bytes + 255) & ~(size_t)255;
        return p;
    };
    float*    ent_emb  = (float*)alloc((size_t)B_ * E_ * H_ * 4);
    float*    ent_attn = (float*)alloc((size_t)B_ * E_ * NH_ * L_ * 4);
    ushort_t* ht_bf    = (ushort_t*)alloc((size_t)B_ * R_ * L_ * 2);
    ushort_t* seq_t    = (ushort_t*)alloc((size_t)B_ * H_ * L_ * 2);
    ushort_t* A1       = (ushort_t*)alloc((size_t)NR_ * 2048 * 2);   // [hs | rel]
    ushort_t* A2       = (ushort_t*)alloc((size_t)NR_ * 2048 * 2);   // [ts | rel] (adjacent)
    ushort_t* Whb      = (ushort_t*)alloc((size_t)EMB_ * 2048 * 2);  // Wh^T bf16
    ushort_t* Wtb      = (ushort_t*)alloc((size_t)EMB_ * 2048 * 2);  // adjacent to Whb
    ushort_t* he_bf    = (ushort_t*)alloc((size_t)NR_ * EMB_ * 2);
    ushort_t* te_bf    = (ushort_t*)alloc((size_t)NR_ * EMB_ * 2);   // adjacent to he_bf
    ushort_t* Wbt      = (ushort_t*)alloc((size_t)EMB_ * KBIG_ * 2); // Wb^T bf16 [768][49152]

    const size_t slice_b = (size_t)NR_ * EMB_ * 4;
    int slices = (ws_size >= off + 8 * slice_b) ? 8 : 1;
    float* embedsN = (float*)alloc((size_t)slices * slice_b);

    // 1) transposed bf16 copies of weights / seq
    k_transpose_cvt<<<dim3(H_ / 64, L_ / 64, B_), 256, 0, stream>>>(seq, seq_t, L_, H_);
    k_transpose_cvt<<<dim3(EMB_ / 64, 2048 / 64, 1), 256, 0, stream>>>(Wh, Whb, 2048, EMB_);
    k_transpose_cvt<<<dim3(EMB_ / 64, 2048 / 64, 1), 256, 0, stream>>>(Wt, Wtb, 2048, EMB_);
    k_transpose_cvt<<<dim3(EMB_ / 64, KBIG_ / 64, 1), 256, 0, stream>>>(Wb, Wbt, KBIG_, EMB_);

    // 2) entity aggregation
    k_ent_emb<<<B_ * E_, 256, 0, stream>>>(entl, labels, ent_emb);
    k_ent_attn<<<B_ * E_ * NH_, 256, 0, stream>>>(attn, labels, ent_attn);

    // 3) pair attention rows + gathers
    k_ht<<<NR_, 256, 0, stream>>>(ent_attn, hts, ht_bf);
    k_gather<<<NR_, 256, 0, stream>>>(ent_emb, hts, A1, A2);

    // 4) rel = ht @ seq  (batched over B), written bf16 into cols 1024.. of A1 and A2
    k_gemm<false, false, true><<<dim3(H_ / 128, R_ / 128, B_), 256, 0, stream>>>(
        ht_bf, (long)R_ * L_, L_,
        seq_t, (long)H_ * L_, L_,
        L_, nullptr, nullptr,
        A1 + 1024, A2 + 1024, (long)R_ * 2048, 2048);

    // 5) he = tanh(A1 @ Wh + bh), te = tanh(A2 @ Wt + bt)   (z selects the pair)
    k_gemm<true, true, false><<<dim3(EMB_ / 128, NR_ / 128, 2), 256, 0, stream>>>(
        A1, (long)NR_ * 2048, 2048,
        Whb, (long)EMB_ * 2048, 2048,
        2048, bh, bt,
        he_bf, nullptr, (long)NR_ * EMB_, EMB_);

    // 6) embeds = bl @ Wb  (A generated on the fly; 8 K-slices XCD-mapped, pipelined)
    if (slices == 1)
        (void)hipMemsetAsync(embedsN, 0, slice_b, stream);
    k_bilinear<<<768, 256, 0, stream>>>(he_bf, te_bf, Wbt, embedsN, slices);

    // 7) out = (sum_z embeds + bb) @ Wc + bc   (fp32)
    k_final<<<NR_, 128, 0, stream>>>(embedsN, slices, bb, Wc, bc, out);
}

// Round 5
// 630.415 us; speedup vs baseline: 1.6124x; 1.1686x over previous
//
#include <hip/hip_runtime.h>
#include <stdint.h>
#include <math.h>

// ---------------- constants ----------------
#define B_    4
#define L_    1024
#define H_    1024
#define NH_   16
#define M_    64
#define E_    24
#define R_    512
#define EMB_  768
#define BLK_  64
#define NCLS_ 97
#define NR_   2048        // B*R
#define KBIG_ 49152       // EMB*BLK  (bilinear GEMM K)

typedef unsigned short ushort_t;
typedef unsigned int uint_t;
typedef short bf16x8 __attribute__((ext_vector_type(8)));
typedef float f32x4  __attribute__((ext_vector_type(4)));
typedef __bf16 bf16v2 __attribute__((ext_vector_type(2)));

__device__ __forceinline__ float bf2f(ushort_t u) {
    return __uint_as_float(((unsigned)u) << 16);
}
__device__ __forceinline__ ushort_t f2bf_rne(float f) {
    unsigned u = __float_as_uint(f);
    return (ushort_t)((u + 0x7fffu + ((u >> 16) & 1u)) >> 16);
}
// async global->LDS 16B/lane; lds base must be wave-uniform (lane lands at +lane*16)
__device__ __forceinline__ void cp16(const void* g, void* l) {
    __builtin_amdgcn_global_load_lds(
        (const __attribute__((address_space(1))) void*)g,
        (__attribute__((address_space(3))) void*)l, 16, 0, 0);
}

// ---------------- transpose + f32->bf16 convert ----------------
// in: f32 [batch][rows][cols] ; out: bf16 [batch][cols][rows]
__global__ __launch_bounds__(256) void k_transpose_cvt(
    const float* __restrict__ in, ushort_t* __restrict__ out, int rows, int cols)
{
    __shared__ float t[64][65];
    int batch = blockIdx.z;
    in  += (size_t)batch * rows * cols;
    out += (size_t)batch * rows * cols;
    int c0 = blockIdx.x * 64, r0 = blockIdx.y * 64;
    int tx = threadIdx.x & 63, ty = threadIdx.x >> 6;   // 64 x 4
#pragma unroll
    for (int dr = 0; dr < 64; dr += 4)
        t[dr + ty][tx] = in[(size_t)(r0 + dr + ty) * cols + (c0 + tx)];
    __syncthreads();
    int c = threadIdx.x >> 2;            // 64 output rows (cols of in)
    int rk = (threadIdx.x & 3) * 16;     // 16 consecutive r per thread
    ushort_t us[16];
#pragma unroll
    for (int q = 0; q < 16; q++) us[q] = f2bf_rne(t[rk + q][c]);
    ushort_t* op = &out[(size_t)(c0 + c) * rows + r0 + rk];
    *reinterpret_cast<int4*>(op)     = *reinterpret_cast<const int4*>(&us[0]);
    *reinterpret_cast<int4*>(op + 8) = *reinterpret_cast<const int4*>(&us[8]);
}

// ---------------- entity embedding: logsumexp over mentions ----------------
__global__ __launch_bounds__(256) void k_ent_emb(
    const float* __restrict__ ent_lhs, const int* __restrict__ labels,
    float* __restrict__ ent_emb)
{
    int b = blockIdx.x / E_, e = blockIdx.x % E_;
    __shared__ int list[M_];
    __shared__ int cnt;
    if (threadIdx.x == 0) cnt = 0;
    __syncthreads();
    if (threadIdx.x < M_ && labels[b * M_ + threadIdx.x] == e) {
        int p = atomicAdd(&cnt, 1);
        list[p] = threadIdx.x;
    }
    __syncthreads();
    int n = cnt;
    const float* base = ent_lhs + (size_t)b * M_ * H_;
    float* outp = ent_emb + ((size_t)b * E_ + e) * H_;
    for (int h = threadIdx.x; h < H_; h += blockDim.x) {
        if (n == 0) { outp[h] = 0.f; continue; }
        float mx = -1e30f;
        for (int i = 0; i < n; i++) mx = fmaxf(mx, base[(size_t)list[i] * H_ + h]);
        float s = 0.f;
        for (int i = 0; i < n; i++) s += __expf(base[(size_t)list[i] * H_ + h] - mx);
        outp[h] = mx + __logf(s);
    }
}

// ---------------- entity attention: mean over mentions ----------------
__global__ __launch_bounds__(256) void k_ent_attn(
    const float* __restrict__ attn, const int* __restrict__ labels,
    float* __restrict__ ent_attn)
{
    int idx = blockIdx.x;                 // b*E*NH + e*NH + nh
    int nh = idx % NH_;
    int be = idx / NH_;
    int e = be % E_, b = be / E_;
    __shared__ int list[M_];
    __shared__ int cnt;
    if (threadIdx.x == 0) cnt = 0;
    __syncthreads();
    if (threadIdx.x < M_ && labels[b * M_ + threadIdx.x] == e) {
        int p = atomicAdd(&cnt, 1);
        list[p] = threadIdx.x;
    }
    __syncthreads();
    int n = cnt;
    float inv = 1.f / fmaxf((float)n, 1.f);
    const float* base = attn + ((size_t)b * NH_ + nh) * M_ * L_;
    float* outp = ent_attn + (((size_t)b * E_ + e) * NH_ + nh) * L_;
    for (int l = threadIdx.x; l < L_; l += blockDim.x) {
        float s = 0.f;
        for (int i = 0; i < n; i++) s += base[(size_t)list[i] * L_ + l];
        outp[l] = s * inv;
    }
}

// ---------------- per-pair ht: mean over heads of ha*ta, row-normalized ----------------
__global__ __launch_bounds__(256) void k_ht(
    const float* __restrict__ ent_attn, const int* __restrict__ hts,
    ushort_t* __restrict__ ht_bf)
{
    int b = blockIdx.x / R_, r = blockIdx.x % R_;
    int h = hts[((size_t)b * R_ + r) * 2 + 0];
    int t = hts[((size_t)b * R_ + r) * 2 + 1];
    const float* ha = ent_attn + ((size_t)b * E_ + h) * NH_ * L_;
    const float* ta = ent_attn + ((size_t)b * E_ + t) * NH_ * L_;
    float vals[4];
    float local = 0.f;
#pragma unroll
    for (int p = 0; p < 4; p++) {
        int l = threadIdx.x + p * 256;
        float s = 0.f;
#pragma unroll
        for (int nh = 0; nh < NH_; nh++) s += ha[nh * L_ + l] * ta[nh * L_ + l];
        s *= (1.f / NH_);
        vals[p] = s;
        local += s;
    }
    __shared__ float red[4];
    float s = local;
#pragma unroll
    for (int off = 32; off > 0; off >>= 1) s += __shfl_down(s, off, 64);
    if ((threadIdx.x & 63) == 0) red[threadIdx.x >> 6] = s;
    __syncthreads();
    float tot = red[0] + red[1] + red[2] + red[3];
    float inv = 1.f / (tot + 1e-5f);
    ushort_t* outp = ht_bf + ((size_t)b * R_ + r) * L_;
#pragma unroll
    for (int p = 0; p < 4; p++) {
        int l = threadIdx.x + p * 256;
        outp[l] = f2bf_rne(vals[p] * inv);
    }
}

// ---------------- gather hs/ts into concat buffers (cols 0..1023) ----------------
__global__ __launch_bounds__(256) void k_gather(
    const float* __restrict__ ent_emb, const int* __restrict__ hts,
    ushort_t* __restrict__ A1, ushort_t* __restrict__ A2)
{
    int n = blockIdx.x;
    int b = n / R_, r = n % R_;
    int h = hts[((size_t)b * R_ + r) * 2 + 0];
    int t = hts[((size_t)b * R_ + r) * 2 + 1];
    const float* eh = ent_emb + ((size_t)b * E_ + h) * H_;
    const float* et = ent_emb + ((size_t)b * E_ + t) * H_;
    for (int i = threadIdx.x; i < H_; i += 256) {
        A1[(size_t)n * 2048 + i] = f2bf_rne(eh[i]);
        A2[(size_t)n * 2048 + i] = f2bf_rne(et[i]);
    }
}

// ---------------- generic bf16 MFMA GEMM (A[M][K] rm  x  Bt[N][K] rm) ----------------
// tile 128x128, 4 waves (2x2 of 64x64), BK=64. Epilogue bounces through LDS for
// 16B vector bf16 stores.
template <bool BIAS, bool TANH, bool DUAL>
__global__ __launch_bounds__(256) void k_gemm(
    const ushort_t* __restrict__ A, long sA, int lda,
    const ushort_t* __restrict__ Bt, long sB, int ldb,
    int K,
    const float* __restrict__ bias0, const float* __restrict__ bias1,
    ushort_t* __restrict__ C0, ushort_t* __restrict__ C1, long sC, int ldc)
{
    __shared__ ushort_t smem[2 * 128 * 72];   // As | Bs ; reused as 128x132 epilogue tile
    ushort_t* As = smem;
    ushort_t* Bs = smem + 128 * 72;
    const int tid = threadIdx.x;
    const int lane = tid & 63, wid = tid >> 6;
    const int wr = wid >> 1, wc = wid & 1;
    const int z = blockIdx.z;
    const int m0 = blockIdx.y * 128, n0 = blockIdx.x * 128;
    A  += (long)z * sA;
    Bt += (long)z * sB;

    const f32x4 zero = {0.f, 0.f, 0.f, 0.f};
    f32x4 acc[4][4];
#pragma unroll
    for (int i = 0; i < 4; i++)
#pragma unroll
        for (int j = 0; j < 4; j++) acc[i][j] = zero;

    const int mrow = wr * 64 + (lane & 15);
    const int nrow = wc * 64 + (lane & 15);
    const int koff = (lane >> 4) * 8;

    for (int k0 = 0; k0 < K; k0 += 64) {
        __syncthreads();
#pragma unroll
        for (int p = 0; p < 4; p++) {
            int idx = tid + p * 256;
            int row = idx >> 3, seg = idx & 7;
            *reinterpret_cast<int4*>(&As[row * 72 + seg * 8]) =
                *reinterpret_cast<const int4*>(&A[(long)(m0 + row) * lda + k0 + seg * 8]);
            *reinterpret_cast<int4*>(&Bs[row * 72 + seg * 8]) =
                *reinterpret_cast<const int4*>(&Bt[(long)(n0 + row) * ldb + k0 + seg * 8]);
        }
        __syncthreads();
#pragma unroll
        for (int ks = 0; ks < 2; ks++) {
            bf16x8 af[4], bfg[4];
#pragma unroll
            for (int mt = 0; mt < 4; mt++)
                af[mt] = *reinterpret_cast<const bf16x8*>(&As[(mrow + mt * 16) * 72 + ks * 32 + koff]);
#pragma unroll
            for (int nt = 0; nt < 4; nt++)
                bfg[nt] = *reinterpret_cast<const bf16x8*>(&Bs[(nrow + nt * 16) * 72 + ks * 32 + koff]);
#pragma unroll
            for (int mt = 0; mt < 4; mt++)
#pragma unroll
                for (int nt = 0; nt < 4; nt++)
                    acc[mt][nt] = __builtin_amdgcn_mfma_f32_16x16x32_bf16(
                        af[mt], bfg[nt], acc[mt][nt], 0, 0, 0);
        }
    }

    // epilogue: bias/tanh -> bf16 -> LDS (stride 132) -> 16B stores
    const float* bias = BIAS ? (z ? bias1 : bias0) : nullptr;
    __syncthreads();
#pragma unroll
    for (int mt = 0; mt < 4; mt++) {
#pragma unroll
        for (int nt = 0; nt < 4; nt++) {
#pragma unroll
            for (int rg = 0; rg < 4; rg++) {
                int row = wr * 64 + mt * 16 + (lane >> 4) * 4 + rg;   // 0..127 local
                int col = wc * 64 + nt * 16 + (lane & 15);            // 0..127 local
                float v = acc[mt][nt][rg];
                if (BIAS) v += bias[n0 + col];
                if (TANH) {
                    float vc = fminf(fmaxf(v, -15.f), 15.f);
                    float ex = __expf(2.f * vc);
                    v = (ex - 1.f) / (ex + 1.f);
                }
                smem[row * 132 + col] = f2bf_rne(v);
            }
        }
    }
    __syncthreads();
    {
        int row = tid >> 1, half = tid & 1;
        const ushort_t* src = &smem[row * 132 + half * 64];
        ushort_t* dst0 = &C0[(long)z * sC + (long)(m0 + row) * ldc + n0 + half * 64];
#pragma unroll
        for (int q = 0; q < 8; q++)
            *reinterpret_cast<int4*>(dst0 + q * 8) = *reinterpret_cast<const int4*>(src + q * 8);
        if (DUAL) {
            ushort_t* dst1 = &C1[(long)z * sC + (long)(m0 + row) * ldc + n0 + half * 64];
#pragma unroll
            for (int q = 0; q < 8; q++)
                *reinterpret_cast<int4*>(dst1 + q * 8) = *reinterpret_cast<const int4*>(src + q * 8);
        }
    }
}

// ---------------- bilinear GEMM, m97-style K-loop ----------------
// embeds[z] = (he (x) te outer-blocks) @ Wb, K-slice z. 768 blocks (96 spatial x 8 z),
// z = bid&7 (one 9.4 MB Wbt window per XCD). Per i: B-tile (128 d-rows x 64 K) staged
// cooperatively into LDS via global_load_lds width-16 (no per-wave duplication, no
// b-frag VGPRs -> 3 blocks/CU -> all 768 blocks co-resident, single lockstep round).
// XOR seg-swizzle (applied on the GLOBAL src address; LDS side must stay unpadded)
// makes ds_read_b128 conflict-free. A-frags generated in regs: te-frag * he-scalar.
__global__ __launch_bounds__(256, 3) void k_bilinear(
    const ushort_t* __restrict__ he, const ushort_t* __restrict__ te,
    const ushort_t* __restrict__ Wbt, float* __restrict__ embedsN, int slices)
{
    __shared__ ushort_t HEs[128 * 72];
    __shared__ ushort_t Bsh[128 * 64];     // B-tile: 128 d-rows x 64 K (bf16), unpadded
    const int tid = threadIdx.x;
    const int lane = tid & 63, wid = tid >> 6;
    const int wr = wid >> 1, wc = wid & 1;
    const int bid = blockIdx.x;
    const int z = bid & 7;                 // K-slice == XCD
    const int w = bid >> 3;
    const int d0 = (w % 6) * 128, n0 = (w / 6) * 128;
    const int c0 = z * 96, cend = c0 + 96;

    const f32x4 zero = {0.f, 0.f, 0.f, 0.f};
    f32x4 acc[4][4];
#pragma unroll
    for (int i = 0; i < 4; i++)
#pragma unroll
        for (int j = 0; j < 4; j++) acc[i][j] = zero;

    const int r15 = lane & 15;
    const int q4 = lane >> 4;
    const int mrow = wr * 64 + r15;        // A-frag row (n of embeds)
    const int koff = q4 * 8;

    // per-lane global base for B staging: lane covers row wid*32 + (lane>>3),
    // seg slot (lane&7) holds global seg (lane&7)^((lane>>3)&7)  [xor swizzle]
    const ushort_t* Pg = Wbt
        + (long)(d0 + wid * 32 + (lane >> 3)) * KBIG_
        + ((lane & 7) ^ ((lane >> 3) & 7)) * 8;
    ushort_t* Pl = Bsh + wid * 2048;       // wave-uniform LDS base (+r*512)

    int c = c0;
    while (c < cend) {
        const int kk = c >> 6;
        const int i0 = c & 63;
        const int i1 = min(64, i0 + (cend - c));

        // stage he[n0..n0+128][kk*64..+64] into LDS (row-major, stride 72)
        __syncthreads();
#pragma unroll
        for (int p = 0; p < 4; p++) {
            int idx = tid + p * 256;
            int row = idx >> 3, seg = idx & 7;
            *reinterpret_cast<int4*>(&HEs[row * 72 + seg * 8]) =
                *reinterpret_cast<const int4*>(&he[(long)(n0 + row) * EMB_ + kk * 64 + seg * 8]);
        }
        __syncthreads();

        // te fragments for this kk-group: global -> registers (reused over all i)
        uint4 tef[4][2];
#pragma unroll
        for (int mt = 0; mt < 4; mt++)
#pragma unroll
            for (int ks = 0; ks < 2; ks++)
                tef[mt][ks] = *reinterpret_cast<const uint4*>(
                    &te[(long)(n0 + mrow + mt * 16) * EMB_ + kk * 64 + ks * 32 + koff]);

        for (int i = i0; i < i1; i++) {
            // async-stage B-tile for this i: Wbt[d0..d0+127][(kk*64+i)*64 .. +64]
            const ushort_t* g = Pg + (long)(kk * 64 + i) * 64;
            cp16(g,              Pl);
            cp16(g +  8 * KBIG_, Pl + 512);
            cp16(g + 16 * KBIG_, Pl + 1024);
            cp16(g + 24 * KBIG_, Pl + 1536);
            __syncthreads();   // drains vmcnt -> B-tile visible

#pragma unroll
            for (int ks = 0; ks < 2; ks++) {
                const int segoff = (((ks * 4 + q4) ^ (r15 & 7)) * 8);
                bf16x8 bfr[4];
#pragma unroll
                for (int nt = 0; nt < 4; nt++)
                    bfr[nt] = *reinterpret_cast<const bf16x8*>(
                        &Bsh[(wc * 64 + nt * 16 + r15) * 64 + segoff]);
#pragma unroll
                for (int mt = 0; mt < 4; mt++) {
                    union { ushort_t s[2]; bf16v2 v; } hu;
                    ushort_t hb = HEs[(mrow + mt * 16) * 72 + i];
                    hu.s[0] = hb; hu.s[1] = hb;
                    union U { uint4 q; bf16v2 p[4]; bf16x8 v; };
                    U t, a;
                    t.q = tef[mt][ks];
#pragma unroll
                    for (int qq = 0; qq < 4; qq++) a.p[qq] = t.p[qq] * hu.v;
#pragma unroll
                    for (int nt = 0; nt < 4; nt++)
                        acc[mt][nt] = __builtin_amdgcn_mfma_f32_16x16x32_bf16(
                            a.v, bfr[nt], acc[mt][nt], 0, 0, 0);
                }
            }
            __syncthreads();   // all waves done reading Bsh before next i overwrites
        }
        c += (i1 - i0);
    }

    // epilogue: plain fp32 stores into slice z (slices==8), else atomic into slice 0
    float* outp = embedsN + (slices == 8 ? (long)z * NR_ * EMB_ : 0l);
    const bool plain = (slices == 8);
#pragma unroll
    for (int mt = 0; mt < 4; mt++)
#pragma unroll
        for (int nt = 0; nt < 4; nt++)
#pragma unroll
            for (int rg = 0; rg < 4; rg++) {
                int n = n0 + wr * 64 + mt * 16 + q4 * 4 + rg;
                int d = d0 + wc * 64 + nt * 16 + r15;
                if (plain) outp[(long)n * EMB_ + d] = acc[mt][nt][rg];
                else       atomicAdd(&outp[(long)n * EMB_ + d], acc[mt][nt][rg]);
            }
}

// ---------------- final head: out = (sum_z embeds + bb) @ Wc + bc  (fp32) ----------------
__global__ __launch_bounds__(128) void k_final(
    const float* __restrict__ embedsN, int nz, const float* __restrict__ bb,
    const float* __restrict__ Wc, const float* __restrict__ bc,
    float* __restrict__ out)
{
    int n = blockIdx.x;
    __shared__ float row[EMB_];
    for (int i = threadIdx.x; i < EMB_; i += 128) {
        float s = bb[i];
        for (int zz = 0; zz < nz; zz++)
            s += embedsN[(size_t)zz * NR_ * EMB_ + (size_t)n * EMB_ + i];
        row[i] = s;
    }
    __syncthreads();
    int j = threadIdx.x;
    if (j < NCLS_) {
        float s = bc[j];
#pragma unroll 8
        for (int d = 0; d < EMB_; d++) s += row[d] * Wc[d * NCLS_ + j];
        out[(size_t)n * NCLS_ + j] = s;
    }
}

// ---------------- launcher ----------------
extern "C" void kernel_launch(void* const* d_in, const int* in_sizes, int n_in,
                              void* d_out, int out_size, void* d_ws, size_t ws_size,
                              hipStream_t stream)
{
    (void)in_sizes; (void)n_in; (void)out_size;
    const float* seq    = (const float*)d_in[0];
    const float* entl   = (const float*)d_in[1];
    const float* attn   = (const float*)d_in[2];
    const int*   labels = (const int*)d_in[3];
    const int*   hts    = (const int*)d_in[4];
    const float* Wh     = (const float*)d_in[5];
    const float* bh     = (const float*)d_in[6];
    const float* Wt     = (const float*)d_in[7];
    const float* bt     = (const float*)d_in[8];
    const float* Wb     = (const float*)d_in[9];
    const float* bb     = (const float*)d_in[10];
    const float* Wc     = (const float*)d_in[11];
    const float* bc     = (const float*)d_in[12];
    float* out = (float*)d_out;

    char* ws = (char*)d_ws;
    size_t off = 0;
    auto alloc = [&](size_t bytes) -> char* {
        char* p = ws + off;
        off += (bytes + 255) & ~(size_t)255;
        return p;
    };
    float*    ent_emb  = (float*)alloc((size_t)B_ * E_ * H_ * 4);
    float*    ent_attn = (float*)alloc((size_t)B_ * E_ * NH_ * L_ * 4);
    ushort_t* ht_bf    = (ushort_t*)alloc((size_t)B_ * R_ * L_ * 2);
    ushort_t* seq_t    = (ushort_t*)alloc((size_t)B_ * H_ * L_ * 2);
    ushort_t* A1       = (ushort_t*)alloc((size_t)NR_ * 2048 * 2);   // [hs | rel]
    ushort_t* A2       = (ushort_t*)alloc((size_t)NR_ * 2048 * 2);   // [ts | rel] (adjacent)
    ushort_t* Whb      = (ushort_t*)alloc((size_t)EMB_ * 2048 * 2);  // Wh^T bf16
    ushort_t* Wtb      = (ushort_t*)alloc((size_t)EMB_ * 2048 * 2);  // adjacent to Whb
    ushort_t* he_bf    = (ushort_t*)alloc((size_t)NR_ * EMB_ * 2);
    ushort_t* te_bf    = (ushort_t*)alloc((size_t)NR_ * EMB_ * 2);   // adjacent to he_bf
    ushort_t* Wbt      = (ushort_t*)alloc((size_t)EMB_ * KBIG_ * 2); // Wb^T bf16 [768][49152]

    const size_t slice_b = (size_t)NR_ * EMB_ * 4;
    int slices = (ws_size >= off + 8 * slice_b) ? 8 : 1;
    float* embedsN = (float*)alloc((size_t)slices * slice_b);

    // 1) transposed bf16 copies of weights / seq
    k_transpose_cvt<<<dim3(H_ / 64, L_ / 64, B_), 256, 0, stream>>>(seq, seq_t, L_, H_);
    k_transpose_cvt<<<dim3(EMB_ / 64, 2048 / 64, 1), 256, 0, stream>>>(Wh, Whb, 2048, EMB_);
    k_transpose_cvt<<<dim3(EMB_ / 64, 2048 / 64, 1), 256, 0, stream>>>(Wt, Wtb, 2048, EMB_);
    k_transpose_cvt<<<dim3(EMB_ / 64, KBIG_ / 64, 1), 256, 0, stream>>>(Wb, Wbt, KBIG_, EMB_);

    // 2) entity aggregation
    k_ent_emb<<<B_ * E_, 256, 0, stream>>>(entl, labels, ent_emb);
    k_ent_attn<<<B_ * E_ * NH_, 256, 0, stream>>>(attn, labels, ent_attn);

    // 3) pair attention rows + gathers
    k_ht<<<NR_, 256, 0, stream>>>(ent_attn, hts, ht_bf);
    k_gather<<<NR_, 256, 0, stream>>>(ent_emb, hts, A1, A2);

    // 4) rel = ht @ seq  (batched over B), written bf16 into cols 1024.. of A1 and A2
    k_gemm<false, false, true><<<dim3(H_ / 128, R_ / 128, B_), 256, 0, stream>>>(
        ht_bf, (long)R_ * L_, L_,
        seq_t, (long)H_ * L_, L_,
        L_, nullptr, nullptr,
        A1 + 1024, A2 + 1024, (long)R_ * 2048, 2048);

    // 5) he = tanh(A1 @ Wh + bh), te = tanh(A2 @ Wt + bt)   (z selects the pair)
    k_gemm<true, true, false><<<dim3(EMB_ / 128, NR_ / 128, 2), 256, 0, stream>>>(
        A1, (long)NR_ * 2048, 2048,
        Whb, (long)EMB_ * 2048, 2048,
        2048, bh, bt,
        he_bf, nullptr, (long)NR_ * EMB_, EMB_);

    // 6) embeds = bl @ Wb  (m97-style staged K-loop; 8 K-slices XCD-mapped)
    if (slices == 1)
        (void)hipMemsetAsync(embedsN, 0, slice_b, stream);
    k_bilinear<<<768, 256, 0, stream>>>(he_bf, te_bf, Wbt, embedsN, slices);

    // 7) out = (sum_z embeds + bb) @ Wc + bc   (fp32)
    k_final<<<NR_, 128, 0, stream>>>(embedsN, slices, bb, Wc, bc, out);
}